// Round 2
// baseline (476.066 us; speedup 1.0000x reference)
//
#include <hip/hip_runtime.h>
#include <hip/hip_bf16.h>

#define VOCAB 256
#define EMB   32
#define HID   128
#define GATES 512
#define BATCH 512
#define SEQ   512

typedef __attribute__((ext_vector_type(8))) short bf16x8;
typedef __attribute__((ext_vector_type(4))) float f32x4;

static __device__ __forceinline__ unsigned short f2bf(float f) {
  unsigned int u = __float_as_uint(f);
  return (unsigned short)((u + 0x7fffu + ((u >> 16) & 1u)) >> 16);
}

// ws layout: P[VOCAB][GATES] f32 (512 KB) | Whh_bf16[GATES][HID] (128 KB)
__global__ __launch_bounds__(256) void prep_kernel(
    const float* __restrict__ emb, const float* __restrict__ W_ih,
    const float* __restrict__ W_hh, const float* __restrict__ b_ih,
    const float* __restrict__ b_hh, float* __restrict__ P,
    unsigned short* __restrict__ Whh_bf) {
  const int wg  = blockIdx.x;
  const int tid = threadIdx.x;
  if (wg < VOCAB) {
    __shared__ float e[EMB];
    if (tid < EMB) e[tid] = emb[wg * EMB + tid];
    __syncthreads();
    for (int g = tid; g < GATES; g += 256) {
      float acc = b_ih[g] + b_hh[g];
      const float* w = W_ih + g * EMB;
      #pragma unroll
      for (int k = 0; k < EMB; ++k) acc += e[k] * w[k];
      P[wg * GATES + g] = acc;
    }
  } else {
    // 64 WGs convert W_hh (65536 f32) to bf16: 1024 elems/WG, 4/thread
    const int base = (wg - VOCAB) * 1024 + tid * 4;
    const float4 v = *(const float4*)(W_hh + base);
    ushort4 o;
    o.x = f2bf(v.x); o.y = f2bf(v.y); o.z = f2bf(v.z); o.w = f2bf(v.w);
    *(ushort4*)(Whh_bf + base) = o;
  }
}

// 256 WGs x 256 threads; WG owns batch rows {2*wg, 2*wg+1}.
// Wave w computes gate-type w (gates [128w, 128w+128)) via 8 n-tiles x 4 k-steps.
// MFMA M=16 (rows 0,1 real, rows 2-15 zero-padded in h_pad LDS).
__global__ __launch_bounds__(256, 1) void lstm_kernel(
    const int* __restrict__ inputs, const float* __restrict__ P,
    const unsigned short* __restrict__ Whh_bf,
    const float* __restrict__ W_cls, const float* __restrict__ b_cls,
    float* __restrict__ out) {
  const int wg   = blockIdx.x;
  const int tid  = threadIdx.x;
  const int wave = tid >> 6;   // 0..3 = gate type (i,f,g,o)
  const int lane = tid & 63;
  const int c16  = lane & 15;  // MFMA m/n lane index
  const int kg   = lane >> 4;  // MFMA k-group
  const int b0   = wg * 2;

  __shared__ unsigned char chars[2][SEQ];        // 1 KB
  __shared__ unsigned short h_pad[16 * 136];     // 4.25 KB bf16 bits, +8 pad vs 128 to break bank conflict
  __shared__ float gates_lds[4][128][2];         // [gtype][j][row]  4 KB
  __shared__ float h_last[2][HID];               // 1 KB

  // stage char indices (int32 per harness) as bytes
  for (int k = tid; k < 2 * SEQ; k += 256) {
    const int r = k >> 9, t = k & (SEQ - 1);
    chars[r][t] = (unsigned char)(inputs[(b0 + r) * SEQ + t] & 0xff);
  }
  // zero h_pad (pad rows stay zero forever -> pad MFMA rows are exact zeros)
  for (int k = tid; k < 16 * 136; k += 256) h_pad[k] = 0;

  // W_hh B-frags resident in registers: B[k][g] = W_hh[g][k]
  // lane (c16,kg) of frag[u][ks] holds W_hh[g = wave*128+u*16+c16][k = ks*32+kg*8 .. +7]
  bf16x8 Bfrag[8][4];
  #pragma unroll
  for (int u = 0; u < 8; ++u) {
    const int g = wave * 128 + u * 16 + c16;
    #pragma unroll
    for (int ks = 0; ks < 4; ++ks)
      Bfrag[u][ks] = *(const bf16x8*)(Whh_bf + g * HID + ks * 32 + kg * 8);
  }

  // gate-math ownership: thread -> (row, j)
  const int row = tid >> 7;
  const int j   = tid & 127;
  float cstate = 0.f;

  __syncthreads();

  #pragma unroll 1
  for (int t = 0; t < SEQ; ++t) {
    // prefetch P rows for this step (consumed after the mid barrier)
    const int ch = chars[row][t];
    const float* Pr = P + ch * GATES + j;
    const float p0 = Pr[0];
    const float p1 = Pr[128];
    const float p2 = Pr[256];
    const float p3 = Pr[384];

    // h(t-1) @ W_hh^T for this wave's 128 gates
    f32x4 acc[8] = {};
    #pragma unroll
    for (int ks = 0; ks < 4; ++ks) {
      const bf16x8 A = *(const bf16x8*)(h_pad + c16 * 136 + ks * 32 + kg * 8);
      #pragma unroll
      for (int u = 0; u < 8; ++u)
        acc[u] = __builtin_amdgcn_mfma_f32_16x16x32_bf16(A, Bfrag[u][ks], acc[u], 0, 0, 0);
    }
    // real rows live at lanes 0-15, acc regs 0,1 (D: row=(lane>>4)*4+reg, col=lane&15)
    if (lane < 16) {
      #pragma unroll
      for (int u = 0; u < 8; ++u)
        *(float2*)&gates_lds[wave][u * 16 + c16][0] = make_float2(acc[u][0], acc[u][1]);
    }
    __syncthreads();

    // dense gate math: one (row, j) per thread
    const float ip = gates_lds[0][j][row] + p0;
    const float fp = gates_lds[1][j][row] + p1;
    const float gp = gates_lds[2][j][row] + p2;
    const float op = gates_lds[3][j][row] + p3;
    const float iv = 1.f / (1.f + __expf(-ip));
    const float fv = 1.f / (1.f + __expf(-fp));
    const float gv = 1.f - 2.f / (__expf(2.f * gp) + 1.f);   // tanh
    const float ov = 1.f / (1.f + __expf(-op));
    cstate = fv * cstate + iv * gv;
    const float th = 1.f - 2.f / (__expf(2.f * cstate) + 1.f);
    const float hv = ov * th;
    h_pad[row * 136 + j] = f2bf(hv);
    if (t == SEQ - 1) h_last[row][j] = hv;
    __syncthreads();
  }

  // classifier epilogue: out[b][v] = h_last[b] . W_cls[v] + b_cls[v]
  #pragma unroll
  for (int half = 0; half < 2; ++half) {
    const int v = j + half * 128;
    float acc = b_cls[v];
    const float4* w  = (const float4*)(W_cls + v * HID);
    const float4* hh = (const float4*)&h_last[row][0];
    #pragma unroll
    for (int k = 0; k < HID / 4; ++k) {
      const float4 wv = w[k];
      const float4 hv4 = hh[k];
      acc += wv.x * hv4.x + wv.y * hv4.y + wv.z * hv4.z + wv.w * hv4.w;
    }
    out[(b0 + row) * VOCAB + v] = acc;
  }
}

extern "C" void kernel_launch(void* const* d_in, const int* in_sizes, int n_in,
                              void* d_out, int out_size, void* d_ws, size_t ws_size,
                              hipStream_t stream) {
  const int*   inputs = (const int*)d_in[0];
  const float* emb    = (const float*)d_in[1];
  const float* W_ih   = (const float*)d_in[2];
  const float* W_hh   = (const float*)d_in[3];
  const float* b_ih   = (const float*)d_in[4];
  const float* b_hh   = (const float*)d_in[5];
  const float* W_cls  = (const float*)d_in[6];
  const float* b_cls  = (const float*)d_in[7];
  float* outp = (float*)d_out;

  float* Ptab = (float*)d_ws;
  unsigned short* Whh_bf = (unsigned short*)((char*)d_ws + VOCAB * GATES * sizeof(float));

  prep_kernel<<<VOCAB + 64, 256, 0, stream>>>(emb, W_ih, W_hh, b_ih, b_hh, Ptab, Whh_bf);
  lstm_kernel<<<BATCH / 2, 256, 0, stream>>>(inputs, Ptab, Whh_bf, W_cls, b_cls, outp);
}

// Round 3
// 365.176 us; speedup vs baseline: 1.3037x; 1.3037x over previous
//
#include <hip/hip_runtime.h>
#include <hip/hip_bf16.h>

#define VOCAB 256
#define EMB   32
#define HID   128
#define GATES 512
#define BATCH 512
#define SEQ   512

typedef __attribute__((ext_vector_type(8))) short bf16x8;
typedef __attribute__((ext_vector_type(4))) float f32x4;

static __device__ __forceinline__ unsigned short f2bf(float f) {
  unsigned int u = __float_as_uint(f);
  return (unsigned short)((u + 0x7fffu + ((u >> 16) & 1u)) >> 16);
}

// ws layout: P[VOCAB][GATES] f32 (512 KB) | Whh_bf16[GATES][HID] (128 KB)
__global__ __launch_bounds__(256) void prep_kernel(
    const float* __restrict__ emb, const float* __restrict__ W_ih,
    const float* __restrict__ W_hh, const float* __restrict__ b_ih,
    const float* __restrict__ b_hh, float* __restrict__ P,
    unsigned short* __restrict__ Whh_bf) {
  const int wg  = blockIdx.x;
  const int tid = threadIdx.x;
  if (wg < VOCAB) {
    __shared__ float e[EMB];
    if (tid < EMB) e[tid] = emb[wg * EMB + tid];
    __syncthreads();
    for (int g = tid; g < GATES; g += 256) {
      float acc = b_ih[g] + b_hh[g];
      const float* w = W_ih + g * EMB;
      #pragma unroll
      for (int k = 0; k < EMB; ++k) acc += e[k] * w[k];
      P[wg * GATES + g] = acc;
    }
  } else {
    const int base = (wg - VOCAB) * 1024 + tid * 4;
    const float4 v = *(const float4*)(W_hh + base);
    ushort4 o;
    o.x = f2bf(v.x); o.y = f2bf(v.y); o.z = f2bf(v.z); o.w = f2bf(v.w);
    *(ushort4*)(Whh_bf + base) = o;
  }
}

// 256 WGs x 256 threads; WG owns batch rows {2*wg, 2*wg+1}.
// Wave w owns gate COLUMNS j in [32w, 32w+32) for ALL 4 gate types:
//   u = gt*2 + jh  ->  n-tile base = gt*128 + w*32 + jh*16.
// A-operand row m reads h[m&1] (replication via address), so D reg r = gates
// of batch row (r&1) in every lane group. Lane (c16,kg) owns the single
// output (row = kg>>1, j = 32w + (kg&1)*16 + c16): gate math is wave-local,
// ONE barrier per step, no gates LDS.
__global__ __launch_bounds__(256, 1) void lstm_kernel(
    const int* __restrict__ inputs, const float* __restrict__ P,
    const unsigned short* __restrict__ Whh_bf,
    const float* __restrict__ W_cls, const float* __restrict__ b_cls,
    float* __restrict__ out) {
  const int wg   = blockIdx.x;
  const int tid  = threadIdx.x;
  const int wave = tid >> 6;
  const int lane = tid & 63;
  const int c16  = lane & 15;
  const int kg   = lane >> 4;
  const int b0   = wg * 2;

  const int row   = kg >> 1;                       // this lane's batch row
  const int jh    = kg & 1;                        // j-half within wave block
  const int jfull = wave * 32 + jh * 16 + c16;     // 0..127 hidden index

  __shared__ unsigned char  chars[2][SEQ];         // 1 KB
  __shared__ unsigned short hbuf[2][2][HID];       // [buf][row][k] bf16, 1 KB
  __shared__ float          h_last[2][HID];        // 1 KB (f32 h for classifier)

  // stage char indices
  for (int k = tid; k < 2 * SEQ; k += 256) {
    const int r = k >> 9, t = k & (SEQ - 1);
    chars[r][t] = (unsigned char)(inputs[(b0 + r) * SEQ + t] & 0xff);
  }
  // zero hbuf[0] (= h(-1)); hbuf[1] first written before first read
  ((unsigned short*)hbuf)[tid] = 0;   // 256 threads cover exactly hbuf[0]

  // B-frags resident in registers: lane (c16,kg) of Bfrag[u][ks] holds
  // W_hh[g = n_base(u)+c16][k = ks*32+kg*8 .. +7]
  bf16x8 Bfrag[8][4];
  #pragma unroll
  for (int gt = 0; gt < 4; ++gt)
    #pragma unroll
    for (int jhu = 0; jhu < 2; ++jhu) {
      const int g = gt * 128 + wave * 32 + jhu * 16 + c16;
      #pragma unroll
      for (int ks = 0; ks < 4; ++ks)
        Bfrag[gt * 2 + jhu][ks] = *(const bf16x8*)(Whh_bf + g * HID + ks * 32 + kg * 8);
    }

  // loop-invariant addresses
  const int aoff = (c16 & 1) * HID + kg * 8;       // shorts into hbuf[rb]
  const float* Pj = P + jfull;
  float cstate = 0.f;

  __syncthreads();

  #pragma unroll 1
  for (int t = 0; t < SEQ; ++t) {
    const int rb = t & 1;
    // P prefetch (L2-resident; consumed ~620 cyc later)
    const int ch = chars[row][t];
    const float* Pr = Pj + ch * GATES;
    const float p0 = Pr[0];
    const float p1 = Pr[128];
    const float p2 = Pr[256];
    const float p3 = Pr[384];

    // h(t-1) @ W_hh^T : A row m = h[m&1] (broadcast read, conflict-free)
    const unsigned short* hb = &hbuf[rb][0][0] + aoff;
    f32x4 acc[8] = {};
    #pragma unroll
    for (int ks = 0; ks < 4; ++ks) {
      const bf16x8 A = *(const bf16x8*)(hb + ks * 32);
      #pragma unroll
      for (int u = 0; u < 8; ++u)
        acc[u] = __builtin_amdgcn_mfma_f32_16x16x32_bf16(A, Bfrag[u][ks], acc[u], 0, 0, 0);
    }

    // select this lane's 4 gates: u = gt*2+jh, reg = row (compile-time idx only)
    const float gi = jh ? (row ? acc[1][1] : acc[1][0]) : (row ? acc[0][1] : acc[0][0]);
    const float gf = jh ? (row ? acc[3][1] : acc[3][0]) : (row ? acc[2][1] : acc[2][0]);
    const float gg = jh ? (row ? acc[5][1] : acc[5][0]) : (row ? acc[4][1] : acc[4][0]);
    const float go = jh ? (row ? acc[7][1] : acc[7][0]) : (row ? acc[6][1] : acc[6][0]);

    const float ip = gi + p0;
    const float fp = gf + p1;
    const float gp = gg + p2;
    const float op = go + p3;
    const float iv = 1.f / (1.f + __expf(-ip));
    const float fv = 1.f / (1.f + __expf(-fp));
    const float gv = 1.f - 2.f / (__expf(2.f * gp) + 1.f);   // tanh
    const float ov = 1.f / (1.f + __expf(-op));
    cstate = fv * cstate + iv * gv;
    const float th = 1.f - 2.f / (__expf(2.f * cstate) + 1.f);
    const float hv = ov * th;

    hbuf[rb ^ 1][row][jfull] = f2bf(hv);
    if (t == SEQ - 1) h_last[row][jfull] = hv;
    __syncthreads();
  }

  // classifier: out[b][v] = h_last[b] . W_cls[v] + b_cls[v]
  const int erow = tid >> 7;
  const int ej   = tid & 127;
  #pragma unroll
  for (int half = 0; half < 2; ++half) {
    const int v = ej + half * 128;
    float acc = b_cls[v];
    const float4* w  = (const float4*)(W_cls + v * HID);
    const float4* hh = (const float4*)&h_last[erow][0];
    #pragma unroll
    for (int k = 0; k < HID / 4; ++k) {
      const float4 wv = w[k];
      const float4 hv4 = hh[k];
      acc += wv.x * hv4.x + wv.y * hv4.y + wv.z * hv4.z + wv.w * hv4.w;
    }
    out[(b0 + erow) * VOCAB + v] = acc;
  }
}

extern "C" void kernel_launch(void* const* d_in, const int* in_sizes, int n_in,
                              void* d_out, int out_size, void* d_ws, size_t ws_size,
                              hipStream_t stream) {
  const int*   inputs = (const int*)d_in[0];
  const float* emb    = (const float*)d_in[1];
  const float* W_ih   = (const float*)d_in[2];
  const float* W_hh   = (const float*)d_in[3];
  const float* b_ih   = (const float*)d_in[4];
  const float* b_hh   = (const float*)d_in[5];
  const float* W_cls  = (const float*)d_in[6];
  const float* b_cls  = (const float*)d_in[7];
  float* outp = (float*)d_out;

  float* Ptab = (float*)d_ws;
  unsigned short* Whh_bf = (unsigned short*)((char*)d_ws + VOCAB * GATES * sizeof(float));

  prep_kernel<<<VOCAB + 64, 256, 0, stream>>>(emb, W_ih, W_hh, b_ih, b_hh, Ptab, Whh_bf);
  lstm_kernel<<<BATCH / 2, 256, 0, stream>>>(inputs, Ptab, Whh_bf, W_cls, b_cls, outp);
}